// Round 1
// baseline (113.789 us; speedup 1.0000x reference)
//
#include <hip/hip_runtime.h>

#define NB 32
#define LL 4096
#define EMB 512
#define DK 256
#define DV 512
#define VOC 32768
#define EPS_ 1e-6f

typedef short bf16x8 __attribute__((ext_vector_type(8)));
typedef float f32x4 __attribute__((ext_vector_type(4)));

__device__ __forceinline__ unsigned short f2bf(float f){
    unsigned int u = __float_as_uint(f);
    return (unsigned short)((u + 0x7FFFu + ((u >> 16) & 1u)) >> 16);
}
__device__ __forceinline__ float bflo(unsigned int k){ return __uint_as_float(k << 16); }
__device__ __forceinline__ float bfhi(unsigned int k){ return __uint_as_float(k & 0xFFFF0000u); }
__device__ __forceinline__ float phi_(float x){ return x > 0.f ? x + 1.f : __expf(x); }

// ---------------- kernel 0: Wk_w [512][256] f32 -> WkT2 blocked bf16 [kt][n][32] ----------------
__global__ void k0_twk(const float* __restrict__ Wk_w, unsigned short* __restrict__ WkT2){
    int kt = blockIdx.x;      // 0..15
    int n  = threadIdx.x;     // 0..255
    unsigned int w[16];
#pragma unroll
    for(int i = 0; i < 16; i++){
        float a = Wk_w[(kt*32 + 2*i    )*DK + n];
        float b = Wk_w[(kt*32 + 2*i + 1)*DK + n];
        w[i] = (unsigned int)f2bf(a) | ((unsigned int)f2bf(b) << 16);
    }
    uint4* dst = (uint4*)(WkT2 + (kt*256 + n)*32);
#pragma unroll
    for(int qd = 0; qd < 4; qd++)
        dst[qd] = make_uint4(w[qd*4], w[qd*4+1], w[qd*4+2], w[qd*4+3]);
}

// ---------------- kernel 1: Q[b][d] = phi(emb[q[b]] @ Wq_w + Wq_b) -> bf16 ----------------
__global__ void k1_q(const int* __restrict__ q, const float* __restrict__ emb,
                     const float* __restrict__ Wq_w, const float* __restrict__ Wq_b,
                     unsigned short* __restrict__ Qbf){
    __shared__ float qe[EMB];
    int b = blockIdx.x, t = threadIdx.x;
    int row = q[b];
    qe[t]       = emb[row*EMB + t];
    qe[t + 256] = emb[row*EMB + t + 256];
    __syncthreads();
    float acc = Wq_b[t];
#pragma unroll 8
    for(int e = 0; e < EMB; e++) acc += qe[e] * Wq_w[e*DK + t];
    Qbf[b*DK + t] = f2bf(phi_(acc));
}

// ---------------- kernel 2: K_table = phi(emb_table @ Wk + b)  (MFMA bf16) ----------------
// M=32768 N=256 K=512. Block: BM=64 rows x full N=256, BK=32, 4 waves (each 64x64).
#define AST 40   // LDS row stride in u16 (80 B, 16B-aligned, bank-spread)
__launch_bounds__(256, 2)
__global__ void k2_gemm(const float* __restrict__ A, const unsigned short* __restrict__ WkT2,
                        const float* __restrict__ bias, unsigned short* __restrict__ Kt){
    __shared__ unsigned short As[64*AST];    // 5120 B
    __shared__ unsigned short Bs[256*AST];   // 20480 B
    int tid = threadIdx.x;
    int m0 = blockIdx.x * 64;
    int wv = tid >> 6, l = tid & 63;
    int lr = l & 15, kg = l >> 4;

    f32x4 acc[4][4];
#pragma unroll
    for(int i = 0; i < 4; i++)
#pragma unroll
        for(int j = 0; j < 4; j++){ f32x4 z = {0.f,0.f,0.f,0.f}; acc[i][j] = z; }

    int arow = tid >> 2, aq = tid & 3;
    const float* Aptr = A + (size_t)(m0 + arow) * EMB;

    for(int kt = 0; kt < 16; kt++){
        // stage A (64x32 f32 -> bf16), coalesced float4 reads
#pragma unroll
        for(int p = 0; p < 2; p++){
            float4 v = *(const float4*)(Aptr + kt*32 + aq*4 + p*16);
            unsigned int w0 = (unsigned int)f2bf(v.x) | ((unsigned int)f2bf(v.y) << 16);
            unsigned int w1 = (unsigned int)f2bf(v.z) | ((unsigned int)f2bf(v.w) << 16);
            *(uint2*)(As + arow*AST + aq*4 + p*16) = make_uint2(w0, w1);
        }
        // stage B: thread t owns n=t, all 32 k (contiguous in blocked WkT2)
        {
            const uint4* src = (const uint4*)(WkT2 + (size_t)(kt*256 + tid)*32);
            uint4 b0 = src[0], b1 = src[1], b2 = src[2], b3 = src[3];
            uint4* bd = (uint4*)(Bs + tid*AST);
            bd[0] = b0; bd[1] = b1; bd[2] = b2; bd[3] = b3;
        }
        __syncthreads();

        bf16x8 af[4], bfr[4];
#pragma unroll
        for(int fi = 0; fi < 4; fi++)
            af[fi] = *(const bf16x8*)(As + (fi*16 + lr)*AST + kg*8);
#pragma unroll
        for(int fj = 0; fj < 4; fj++)
            bfr[fj] = *(const bf16x8*)(Bs + (wv*64 + fj*16 + lr)*AST + kg*8);
#pragma unroll
        for(int fi = 0; fi < 4; fi++)
#pragma unroll
            for(int fj = 0; fj < 4; fj++)
                acc[fi][fj] = __builtin_amdgcn_mfma_f32_16x16x32_bf16(af[fi], bfr[fj], acc[fi][fj], 0, 0, 0);
        __syncthreads();
    }

    // epilogue: bias + phi + bf16 store. D map: col=lane&15, row=(lane>>4)*4+reg
#pragma unroll
    for(int fj = 0; fj < 4; fj++){
        int n = wv*64 + fj*16 + lr;
        float bv = bias[n];
#pragma unroll
        for(int fi = 0; fi < 4; fi++){
            int r = m0 + fi*16 + kg*4;
#pragma unroll
            for(int reg = 0; reg < 4; reg++){
                float v = acc[fi][fj][reg] + bv;
                Kt[(size_t)(r + reg)*DK + n] = f2bf(phi_(v));
            }
        }
    }
}

// ---------------- kernel 3: fused s-compute + V-stream ----------------
// grid: 512 blocks = (b=bx>>4, chunk=bx&15), 256 threads, 256 tokens/block
__global__ void k3_fused(const int* __restrict__ kk_, const float* __restrict__ V,
                         const unsigned short* __restrict__ Kt, const unsigned short* __restrict__ Qbf,
                         float* __restrict__ pnum, float* __restrict__ pden){
    __shared__ unsigned int Qs[128];
    __shared__ int kidx[256];
    __shared__ float s_l[256];
    int t = threadIdx.x;
    int b = blockIdx.x >> 4, ch = blockIdx.x & 15;

    if(t < 128) Qs[t] = *(const unsigned int*)(Qbf + b*DK + t*2);
    kidx[t] = kk_[b*LL + ch*256 + t];
    __syncthreads();

    // phase A: s[l] = K_table[kidx[l]] . Q[b]   (16 lanes per token)
    int g = t >> 4, j = t & 15;
    for(int it = 0; it < 16; it++){
        int tk = it*16 + g;
        int row = kidx[tk];
        const uint4* kr = (const uint4*)(Kt + (size_t)row*DK + j*16);
        uint4 v0 = kr[0], v1 = kr[1];
        unsigned int kv[8] = {v0.x, v0.y, v0.z, v0.w, v1.x, v1.y, v1.z, v1.w};
        float p = 0.f;
#pragma unroll
        for(int q2 = 0; q2 < 8; q2++){
            unsigned int qq = Qs[j*8 + q2];
            p += bflo(kv[q2]) * bflo(qq) + bfhi(kv[q2]) * bfhi(qq);
        }
        p += __shfl_xor(p, 1, 16);
        p += __shfl_xor(p, 2, 16);
        p += __shfl_xor(p, 4, 16);
        p += __shfl_xor(p, 8, 16);
        if(j == 0) s_l[tk] = p;
    }
    __syncthreads();

    // den partial (wave 0)
    if(t < 64){
        float d = s_l[t] + s_l[t+64] + s_l[t+128] + s_l[t+192];
#pragma unroll
        for(int off = 32; off; off >>= 1) d += __shfl_down(d, off);
        if(t == 0) pden[ch*32 + b] = d;
    }

    // phase B: num partials. 128 lanes per token (float4), 2 tokens interleaved
    int half = t >> 7, c4 = t & 127;
    const float* vbase = V + (size_t)(b*LL + ch*256) * DV;
    float ax = 0.f, ay = 0.f, az = 0.f, aw = 0.f;
#pragma unroll 4
    for(int i = 0; i < 128; i++){
        int lp = 2*i + half;
        float s = s_l[lp];
        float4 v = *(const float4*)(vbase + (size_t)lp*DV + c4*4);
        ax += s*v.x; ay += s*v.y; az += s*v.z; aw += s*v.w;
    }
    float4 res = make_float4(ax, ay, az, aw);
    *(float4*)(pnum + (size_t)((ch*2 + half)*32 + b)*DV + c4*4) = res;
}

// ---------------- kernel 4: finalize ----------------
__global__ void k4_final(const float* __restrict__ pnum, const float* __restrict__ pden,
                         float* __restrict__ out){
    int b = blockIdx.x, t = threadIdx.x;
    __shared__ float dsh;
    if(t == 0){
        float d = 0.f;
        for(int ch = 0; ch < 16; ch++) d += pden[ch*32 + b];
        dsh = d + EPS_;
    }
    __syncthreads();
    float den = dsh;
    for(int v = t; v < DV; v += 256){
        float num = 0.f;
#pragma unroll
        for(int s = 0; s < 32; s++) num += pnum[(size_t)(s*32 + b)*DV + v];
        out[b*DV + v] = num / den;
    }
}

extern "C" void kernel_launch(void* const* d_in, const int* in_sizes, int n_in,
                              void* d_out, int out_size, void* d_ws, size_t ws_size,
                              hipStream_t stream) {
    const int*   k_    = (const int*)d_in[0];
    const int*   q_    = (const int*)d_in[1];
    const float* v_emb = (const float*)d_in[2];
    const float* emb   = (const float*)d_in[3];
    const float* Wk_w  = (const float*)d_in[4];
    const float* Wk_b  = (const float*)d_in[5];
    const float* Wq_w  = (const float*)d_in[6];
    const float* Wq_b  = (const float*)d_in[7];
    float* out = (float*)d_out;

    char* ws = (char*)d_ws;
    unsigned short* WkT2 = (unsigned short*)(ws);                 //   262144 B
    unsigned short* Qbf  = (unsigned short*)(ws + 262144);        //    16384 B
    unsigned short* Kt   = (unsigned short*)(ws + 278528);        // 16777216 B
    float* pnum          = (float*)(ws + 17055744);               //  2097152 B
    float* pden          = (float*)(ws + 19152896);               //     2048 B
    // total ws usage: 19,154,944 B

    k0_twk <<<16,  256, 0, stream>>>(Wk_w, WkT2);
    k1_q   <<<32,  256, 0, stream>>>(q_, emb, Wq_w, Wq_b, Qbf);
    k2_gemm<<<512, 256, 0, stream>>>(emb, WkT2, Wk_b, Kt);
    k3_fused<<<512,256, 0, stream>>>(k_, v_emb, Kt, Qbf, pnum, pden);
    k4_final<<<32, 256, 0, stream>>>(pnum, pden, out);
}